// Round 38
// baseline (101.531 us; speedup 1.0000x reference)
//
#include <hip/hip_runtime.h>
#include <hip/hip_bf16.h>
#include <cstdint>

#define BB 2
#define TT 2048
#define DMo 1024
#define NH 16
#define HD 64
#define NR (BB*TT)   // 4096 rows

typedef __attribute__((ext_vector_type(8))) short bf16x8;
typedef __attribute__((ext_vector_type(4))) float f32x4;
typedef __attribute__((ext_vector_type(16))) float f32x16;
typedef __attribute__((ext_vector_type(4))) unsigned short u16x4;

static __device__ __forceinline__ float bf2f(unsigned short u) {
    union { unsigned int u32; float f; } x; x.u32 = ((unsigned int)u) << 16; return x.f;
}
static __device__ __forceinline__ unsigned short f2bf(float f) {
    union { float f; unsigned int u; } x; x.f = f;
    unsigned int r = x.u + 0x7fffu + ((x.u >> 16) & 1u);
    return (unsigned short)(r >> 16);
}
// HW packed f32->bf16 (RNE), one VALU op for two values (T12 recipe)
static __device__ __forceinline__ unsigned int cvtpk(float lo, float hi) {
    unsigned int r;
    asm("v_cvt_pk_bf16_f32 %0, %1, %2" : "=v"(r) : "v"(lo), "v"(hi));
    return r;
}

static __device__ __forceinline__ void gload16(const unsigned short* g, unsigned short* l) {
    __builtin_amdgcn_global_load_lds((const __attribute__((address_space(1))) void*)g,
                                     (__attribute__((address_space(3))) void*)l, 16, 0, 0);
}

// ---------------- fused f32 -> bf16 convert for x + 4 weights ----------------
__global__ void cvt_all(const float* __restrict__ x, const float* __restrict__ wq,
                        const float* __restrict__ wk, const float* __restrict__ wv,
                        const float* __restrict__ wo,
                        unsigned short* __restrict__ xb, unsigned short* __restrict__ wqb,
                        unsigned short* __restrict__ wkb, unsigned short* __restrict__ wvb,
                        unsigned short* __restrict__ wob) {
    int bi = blockIdx.x;
    const float* src; unsigned short* dst; int base;
    if (bi < 2048)      { src = x;  dst = xb;  base = 0; }
    else if (bi < 2560) { src = wq; dst = wqb; base = 2048; }
    else if (bi < 3072) { src = wk; dst = wkb; base = 2560; }
    else if (bi < 3584) { src = wv; dst = wvb; base = 3072; }
    else                { src = wo; dst = wob; base = 3584; }
    size_t i = (size_t)(bi - base) * 256 + threadIdx.x;   // 8-elem groups
    const float4* p = reinterpret_cast<const float4*>(src) + 2 * i;
    float4 a = p[0], b = p[1];
    bf16x8 o;
    o[0] = (short)f2bf(a.x); o[1] = (short)f2bf(a.y); o[2] = (short)f2bf(a.z); o[3] = (short)f2bf(a.w);
    o[4] = (short)f2bf(b.x); o[5] = (short)f2bf(b.y); o[6] = (short)f2bf(b.z); o[7] = (short)f2bf(b.w);
    *(reinterpret_cast<bf16x8*>(dst) + i) = o;
}

// ---------------- fused QKV GEMM: BM=128 x BN=192, 384 thr (6 waves 2x3) -----
// grid (16, 32) = 512 blocks -> exactly 2 blocks/CU: uniform 12 waves/CU AND
// a co-resident block to cover each barrier drain. T5 setprio around the MFMA
// cluster: the two co-resident blocks sit at different phases, so the CU
// scheduler can prefer the MFMA-feeding block over the staging one.
__global__ __launch_bounds__(384, 3) void gemm_qkv(
    const unsigned short* __restrict__ A,
    const unsigned short* __restrict__ Wq,
    const unsigned short* __restrict__ Wk,
    const unsigned short* __restrict__ Wv,
    const float* __restrict__ bq, const float* __restrict__ bk, const float* __restrict__ bv,
    const float* __restrict__ tau,
    unsigned short* __restrict__ Qb, unsigned short* __restrict__ Kb,
    unsigned short* __restrict__ Vtb)
{
    __shared__ unsigned short lA[2][128 * 32];
    __shared__ unsigned short lB[2][192 * 32];
    const int K = DMo;
    int tid = threadIdx.x, lane = tid & 63, wid = tid >> 6;
    int l15 = lane & 15, l4 = lane >> 4;
    int wr = wid / 3, wc = wid % 3;           // 2 x 3 wave grid
    int pn = blockIdx.x, bm = blockIdx.y;     // pn 0..15 (192-col panels)
    f32x4 acc[4][4] = {};
    int sA0 = tid, sA1 = tid + 384;
    int rA0 = sA0 >> 2, cA0 = sA0 & 3;
    int rA1 = sA1 >> 2, cA1 = sA1 & 3;
    const unsigned short* pA0 = A + (size_t)(bm * 128 + rA0) * K + ((cA0 ^ (rA0 & 3)) * 8);
    const unsigned short* pA1 = A + (size_t)(bm * 128 + rA1) * K + ((cA1 ^ (rA1 & 3)) * 8);
    int sB0 = tid, sB1 = tid + 384;
    int rB0 = sB0 >> 2, cB0 = sB0 & 3;
    int rB1 = sB1 >> 2, cB1 = sB1 & 3;
    int gr0 = pn * 192 + rB0, gr1 = pn * 192 + rB1;
    int mm0 = gr0 >> 10, mm1 = gr1 >> 10;
    const unsigned short* W0 = (mm0 == 0) ? Wq : ((mm0 == 1) ? Wk : Wv);
    const unsigned short* W1 = (mm1 == 0) ? Wq : ((mm1 == 1) ? Wk : Wv);
    const unsigned short* pB0 = W0 + (size_t)(gr0 & 1023) * K + ((cB0 ^ (rB0 & 3)) * 8);
    const unsigned short* pB1 = W1 + (size_t)(gr1 & 1023) * K + ((cB1 ^ (rB1 & 3)) * 8);
    unsigned short* dA0h0 = lA[0] + sA0 * 8;
    unsigned short* dA1h0 = lA[0] + sA1 * 8;
    unsigned short* dA0h1 = lA[1] + sA0 * 8;
    unsigned short* dA1h1 = lA[1] + sA1 * 8;
    unsigned short* dB0h0 = lB[0] + sB0 * 8;
    unsigned short* dB1h0 = lB[0] + sB1 * 8;
    unsigned short* dB0h1 = lB[1] + sB0 * 8;
    unsigned short* dB1h1 = lB[1] + sB1 * 8;
    int cs = (l4 ^ (l15 & 3)) * 8;             // matching read-side XOR
    bool a2 = (tid < 128);                     // waves 0-1 (wave-uniform)
    for (int k0 = 0; k0 < K; k0 += 64) {
        gload16(pA0 + k0,      dA0h0);
        if (a2) gload16(pA1 + k0,      dA1h0);
        gload16(pA0 + k0 + 32, dA0h1);
        if (a2) gload16(pA1 + k0 + 32, dA1h1);
        gload16(pB0 + k0,      dB0h0);
        gload16(pB1 + k0,      dB1h0);
        gload16(pB0 + k0 + 32, dB0h1);
        gload16(pB1 + k0 + 32, dB1h1);
        __syncthreads();                 // drains vmcnt(0) + barrier (m97-proven)
        __builtin_amdgcn_s_setprio(1);   // T5: prefer MFMA-phase block
#pragma unroll
        for (int kk = 0; kk < 2; ++kk) {
            bf16x8 af[4], bfr[4];
#pragma unroll
            for (int m = 0; m < 4; ++m) af[m]  = *(const bf16x8*)(lA[kk] + (wr * 64 + m * 16 + l15) * 32 + cs);
#pragma unroll
            for (int n = 0; n < 4; ++n) bfr[n] = *(const bf16x8*)(lB[kk] + (wc * 64 + n * 16 + l15) * 32 + cs);
#pragma unroll
            for (int m = 0; m < 4; ++m)
#pragma unroll
                for (int n = 0; n < 4; ++n)
                    acc[m][n] = __builtin_amdgcn_mfma_f32_16x16x32_bf16(af[m], bfr[n], acc[m][n], 0, 0, 0);
        }
        __builtin_amdgcn_s_setprio(0);
        __syncthreads();
    }
    int gcolb = pn * 192 + wc * 64;
    int sel = gcolb >> 10;
    int cb = gcolb & 1023;                     // within-matrix col base
    const float* bias = (sel == 0) ? bq : ((sel == 1) ? bk : bv);
    float bz[4];
#pragma unroll
    for (int n = 0; n < 4; ++n) bz[n] = bias[cb + n * 16 + l15];
    if (sel < 2) {
        unsigned short* Ob = (sel == 0) ? Qb : Kb;
        float tscale = (sel == 0) ? tau[cb >> 6] : 1.0f;
#pragma unroll
        for (int m = 0; m < 4; ++m) {
            int row = bm * 128 + wr * 64 + m * 16 + l4 * 4;
#pragma unroll
            for (int i = 0; i < 4; ++i) {
                float v[4]; float ss = 0.f;
#pragma unroll
                for (int n = 0; n < 4; ++n) { v[n] = acc[m][n][i] + bz[n]; ss += v[n] * v[n]; }
#pragma unroll
                for (int off = 1; off < 16; off <<= 1) ss += __shfl_xor(ss, off);
                float sc = tscale / fmaxf(sqrtf(ss), 1e-12f);
#pragma unroll
                for (int n = 0; n < 4; ++n)
                    Ob[(size_t)(row + i) * DMo + cb + n * 16 + l15] = f2bf(v[n] * sc);
            }
        }
    } else {
#pragma unroll
        for (int m = 0; m < 4; ++m) {
            int row = bm * 128 + wr * 64 + m * 16 + l4 * 4;
#pragma unroll
            for (int n = 0; n < 4; ++n) {
                int col = cb + n * 16 + l15;
                u16x4 pk;
#pragma unroll
                for (int i = 0; i < 4; ++i) pk[i] = f2bf(acc[m][n][i] + bz[n]);
                int b = row >> 11, t = row & 2047;
                int bh = b * NH + (col >> 6), d = col & 63;
                *reinterpret_cast<u16x4*>(Vtb + ((size_t)bh * HD + d) * TT + t) = pk;
            }
        }
    }
}

// ---------------- final GEMM: BK=64, XCD-affine + XOR-swizzled LDS -----------
__global__ __launch_bounds__(256) void gemm_out(
    const unsigned short* __restrict__ A,
    const unsigned short* __restrict__ Bm,
    const float* __restrict__ bias,
    float* __restrict__ Cout)
{
    __shared__ unsigned short lA[2][128 * 32];
    __shared__ unsigned short lB[2][128 * 32];
    const int K = DMo, N = DMo;
    int tid = threadIdx.x, lane = tid & 63, wid = tid >> 6;
    int l15 = lane & 15, l4 = lane >> 4;
    int wr = wid >> 1, wc = wid & 1;
    int lid = blockIdx.x;
    int xcd = lid & 7, idx = lid >> 3;     // idx 0..31
    int bn = idx % 8;
    int bm = (idx / 8) * 8 + xcd;          // XCD-affine A-panel
    f32x4 acc[4][4] = {};
    int sr = tid >> 2;
    int g8 = ((tid & 3) ^ (sr & 3)) * 8;
    const unsigned short* Ar0 = A + (size_t)(bm * 128 + sr) * K + g8;
    const unsigned short* Ar1 = Ar0 + (size_t)64 * K;
    const unsigned short* Br0 = Bm + (size_t)(bn * 128 + sr) * K + g8;
    const unsigned short* Br1 = Br0 + (size_t)64 * K;
    unsigned short* lA0 = lA[0] + tid * 8;
    unsigned short* lA1 = lA[1] + tid * 8;
    unsigned short* lB0 = lB[0] + tid * 8;
    unsigned short* lB1 = lB[1] + tid * 8;
    int cs = (l4 ^ (l15 & 3)) * 8;
    for (int k0 = 0; k0 < K; k0 += 64) {
        gload16(Ar0 + k0,      lA0);
        gload16(Ar1 + k0,      lA0 + 2048);
        gload16(Ar0 + k0 + 32, lA1);
        gload16(Ar1 + k0 + 32, lA1 + 2048);
        gload16(Br0 + k0,      lB0);
        gload16(Br1 + k0,      lB0 + 2048);
        gload16(Br0 + k0 + 32, lB1);
        gload16(Br1 + k0 + 32, lB1 + 2048);
        __syncthreads();
        __builtin_amdgcn_s_setprio(1);
#pragma unroll
        for (int kk = 0; kk < 2; ++kk) {
            bf16x8 af[4], bfr[4];
#pragma unroll
            for (int m = 0; m < 4; ++m) af[m]  = *(const bf16x8*)(lA[kk] + (wr * 64 + m * 16 + l15) * 32 + cs);
#pragma unroll
            for (int n = 0; n < 4; ++n) bfr[n] = *(const bf16x8*)(lB[kk] + (wc * 64 + n * 16 + l15) * 32 + cs);
#pragma unroll
            for (int m = 0; m < 4; ++m)
#pragma unroll
                for (int n = 0; n < 4; ++n)
                    acc[m][n] = __builtin_amdgcn_mfma_f32_16x16x32_bf16(af[m], bfr[n], acc[m][n], 0, 0, 0);
        }
        __builtin_amdgcn_s_setprio(0);
        __syncthreads();
    }
#pragma unroll
    for (int m = 0; m < 4; ++m) {
        int row = bm * 128 + wr * 64 + m * 16 + l4 * 4;
#pragma unroll
        for (int n = 0; n < 4; ++n) {
            int col = bn * 128 + wc * 64 + n * 16 + l15;
            float bz = bias[col];
#pragma unroll
            for (int i = 0; i < 4; ++i)
                Cout[(size_t)(row + i) * N + col] = acc[m][n][i] + bz;
        }
    }
}

// ---------------- flash attention: 8 waves, kv split across wave-groups ------
// (R30-proven; 256 blocks, two sequential qb phases per block)
__global__ __launch_bounds__(512, 1) void attn_fwd(
    const unsigned short* __restrict__ Qn,
    const unsigned short* __restrict__ Kn,
    const unsigned short* __restrict__ Vt,
    const float* __restrict__ tau,
    unsigned short* __restrict__ Out)
{
    __shared__ unsigned short lK[2][2][64][68];   // [ring][parity][row][col]
    __shared__ unsigned short lVt[2][2][64][68];
    __shared__ float lX[4][64][34];               // cross-group exchange
    __shared__ float lInv[4][32];
    int bid = blockIdx.x;
    int xcd = bid & 7, r = bid >> 3;     // r 0..31
    int bh = ((r & 3) << 3) + xcd;
    int jid = r >> 2;                    // 0..7
    int b = bh >> 4, h = bh & 15;
    int tid = threadIdx.x, lane = tid & 63, wid = tid >> 6;
    int grp = wid >> 2, w4 = wid & 3;    // kv-group, q-tile within group
    int l31 = lane & 31, half = lane >> 5;
    float M = fabsf(tau[h]);             // fixed softmax shift

    const unsigned short* Kg = Kn + (size_t)b * TT * DMo + h * HD;
    const unsigned short* Vg = Vt + (size_t)bh * HD * TT;

    int rA = tid >> 3, gA = (tid & 7) * 8;   // 512 thr: 64 rows x 8 chunks

    for (int ph = 0; ph < 2; ++ph) {
        int qb = ph ? jid : (15 - jid);
        int q0 = qb * 128;
        int nt = 2 * qb + 2;
        int nh2 = nt >> 1;               // tiles per group (nt always even)

        size_t qoff = ((size_t)b * TT + q0 + w4 * 32 + l31) * DMo + h * HD;
        bf16x8 qf[4];
#pragma unroll
        for (int ks = 0; ks < 4; ++ks)
            qf[ks] = *(const bf16x8*)(Qn + qoff + ks * 16 + half * 8);

        f32x16 accO[2] = {};
        float l_run = 0.f;

        bf16x8 rk0, rk1, rv0, rv1;       // staging regs for a tile PAIR
        auto ldpair = [&](int jp) {      // tiles 2jp, 2jp+1
            rk0 = *(const bf16x8*)(Kg + (size_t)(2 * jp * 64 + rA) * DMo + gA);
            rk1 = *(const bf16x8*)(Kg + (size_t)((2 * jp + 1) * 64 + rA) * DMo + gA);
            rv0 = *(const bf16x8*)(Vg + (size_t)rA * TT + 2 * jp * 64 + gA);
            rv1 = *(const bf16x8*)(Vg + (size_t)rA * TT + (2 * jp + 1) * 64 + gA);
        };
        auto stpair = [&](int pb) {
            *reinterpret_cast<bf16x8*>(&lK[pb][0][rA][gA])  = rk0;
            *reinterpret_cast<bf16x8*>(&lK[pb][1][rA][gA])  = rk1;
            *reinterpret_cast<bf16x8*>(&lVt[pb][0][rA][gA]) = rv0;
            *reinterpret_cast<bf16x8*>(&lVt[pb][1][rA][gA]) = rv1;
        };
        ldpair(0);
        if (ph == 1) __syncthreads();    // prior phase fully done before ring reuse
        stpair(0);
        if (nh2 > 1) ldpair(1);

        for (int t2 = 0; t2 < nh2; ++t2) {
            int cur = t2 & 1;
            __syncthreads();             // ring[cur] visible; prior reads done
            if (t2 + 1 < nh2) {
                stpair(cur ^ 1);
                if (t2 + 2 < nh2) ldpair(t2 + 2);
            }
            int j = 2 * t2 + grp;        // this group's kv tile
            // S^T = K . Q
            f32x16 s[2] = {};
            __builtin_amdgcn_s_setprio(1);
#pragma unroll
            for (int kvb = 0; kvb < 2; ++kvb)
#pragma unroll
                for (int ks = 0; ks < 4; ++ks) {
                    bf16x8 a = *(const bf16x8*)(&lK[cur][grp][kvb * 32 + l31][ks * 16 + half * 8]);
                    s[kvb] = __builtin_amdgcn_mfma_f32_32x32x16_bf16(a, qf[ks], s[kvb], 0, 0, 0);
                }
            __builtin_amdgcn_s_setprio(0);
            // causal mask only on the diagonal pair (last step; both groups)
            if (t2 == nh2 - 1) {
                int qg = q0 + w4 * 32 + l31;
#pragma unroll
                for (int kvb = 0; kvb < 2; ++kvb)
#pragma unroll
                    for (int rr = 0; rr < 16; ++rr) {
                        int kvg = j * 64 + kvb * 32 + (rr & 3) + 8 * (rr >> 2) + 4 * half;
                        if (kvg > qg) s[kvb][rr] = -1e30f;
                    }
            }
            // fixed-shift softmax; lane-local denominator
            float rs = 0.f;
#pragma unroll
            for (int kvb = 0; kvb < 2; ++kvb)
#pragma unroll
                for (int rr = 0; rr < 16; ++rr) {
                    float p = __expf(s[kvb][rr] - M); s[kvb][rr] = p; rs += p;
                }
            l_run += rs;
            // pack P via v_cvt_pk_bf16_f32
            unsigned int Wp[2][4][2];
#pragma unroll
            for (int kvb = 0; kvb < 2; ++kvb)
#pragma unroll
                for (int jj = 0; jj < 4; ++jj)
#pragma unroll
                    for (int t = 0; t < 2; ++t)
                        Wp[kvb][jj][t] = cvtpk(s[kvb][4 * jj + 2 * t], s[kvb][4 * jj + 2 * t + 1]);
            // build PV A-fragments (permlane32_swap exchanges lane halves)
            bf16x8 pa[4];
#pragma unroll
            for (int kvs = 0; kvs < 4; ++kvs) {
                int c = kvs >> 1, d0 = 2 * (kvs & 1), d1 = d0 + 1;
                unsigned int A0 = half ? Wp[c][d1][0] : Wp[c][d0][0];
                unsigned int A1 = half ? Wp[c][d1][1] : Wp[c][d0][1];
                unsigned int B0 = half ? Wp[c][d0][0] : Wp[c][d1][0];
                unsigned int B1 = half ? Wp[c][d0][1] : Wp[c][d1][1];
                unsigned int x0 = B0, y0 = B0, x1 = B1, y1 = B1;
                asm volatile("v_permlane32_swap_b32 %0, %1" : "+v"(x0), "+v"(y0));
                asm volatile("v_permlane32_swap_b32 %0, %1" : "+v"(x1), "+v"(y1));
                unsigned int P0 = half ? x0 : y0;
                unsigned int P1 = half ? x1 : y1;
                unsigned int paw[4];
                paw[0] = half ? P0 : A0;
                paw[1] = half ? P1 : A1;
                paw[2] = half ? A0 : P0;
                paw[3] = half ? A1 : P1;
                pa[kvs] = *reinterpret_cast<bf16x8*>(paw);
            }
            // O += P . V
            __builtin_amdgcn_s_setprio(1);
#pragma unroll
            for (int dblk = 0; dblk < 2; ++dblk)
#pragma unroll
                for (int kvs = 0; kvs < 4; ++kvs) {
                    bf16x8 bv = *(const bf16x8*)(&lVt[cur][grp][dblk * 32 + l31][kvs * 16 + half * 8]);
                    accO[dblk] = __builtin_amdgcn_mfma_f32_32x32x16_bf16(pa[kvs], bv, accO[dblk], 0, 0, 0);
                }
            __builtin_amdgcn_s_setprio(0);
        }
        // within-wave kv-half combine
        l_run += __shfl_xor(l_run, 32);
        // cross-group combine via LDS: group 1 -> group 0
        if (grp == 1) {
#pragma unroll
            for (int dblk = 0; dblk < 2; ++dblk)
#pragma unroll
                for (int rr = 0; rr < 16; ++rr)
                    lX[w4][lane][dblk * 16 + rr] = accO[dblk][rr];
            if (lane < 32) lX[w4][lane][32] = l_run;
        }
        __syncthreads();
        if (grp == 0) {
#pragma unroll
            for (int dblk = 0; dblk < 2; ++dblk)
#pragma unroll
                for (int rr = 0; rr < 16; ++rr)
                    accO[dblk][rr] += lX[w4][lane][dblk * 16 + rr];
            l_run += lX[w4][l31][32];
            float inv = 1.0f / l_run;
            if (lane < 32) lInv[w4][l31] = inv;   // wave-private slice
            asm volatile("s_waitcnt lgkmcnt(0)" ::: "memory");
            __builtin_amdgcn_sched_barrier(0);
#pragma unroll
            for (int rr = 0; rr < 16; ++rr) {
                int qrow = (rr & 3) + 8 * (rr >> 2) + 4 * half;
                float iv = lInv[w4][qrow];
                size_t rowoff = (size_t)(b * TT + q0 + w4 * 32 + qrow) * DMo + h * HD + l31;
#pragma unroll
                for (int dblk = 0; dblk < 2; ++dblk)
                    Out[rowoff + dblk * 32] = f2bf(accO[dblk][rr] * iv);
            }
        }
    }
}

extern "C" void kernel_launch(void* const* d_in, const int* in_sizes, int n_in,
                              void* d_out, int out_size, void* d_ws, size_t ws_size,
                              hipStream_t stream) {
    const float* x   = (const float*)d_in[0];
    // d_in[1] = mask: pure causal -1e9, handled analytically in attn_fwd
    const float* Wq  = (const float*)d_in[2];
    const float* bq  = (const float*)d_in[3];
    const float* Wk  = (const float*)d_in[4];
    const float* bk  = (const float*)d_in[5];
    const float* Wv  = (const float*)d_in[6];
    const float* bv  = (const float*)d_in[7];
    const float* Wo  = (const float*)d_in[8];
    const float* bo  = (const float*)d_in[9];
    const float* tau = (const float*)d_in[10];

    char* ws = (char*)d_ws;
    unsigned short* xb  = (unsigned short*)(ws);
    unsigned short* Wqb = (unsigned short*)(ws + ((size_t)8  << 20));
    unsigned short* Wkb = (unsigned short*)(ws + ((size_t)10 << 20));
    unsigned short* Wvb = (unsigned short*)(ws + ((size_t)12 << 20));
    unsigned short* Wob = (unsigned short*)(ws + ((size_t)14 << 20));
    unsigned short* Qb  = (unsigned short*)(ws + ((size_t)16 << 20));
    unsigned short* Kb  = (unsigned short*)(ws + ((size_t)24 << 20));
    unsigned short* Vtb = (unsigned short*)(ws + ((size_t)32 << 20));
    unsigned short* AOb = (unsigned short*)(ws + ((size_t)40 << 20));

    cvt_all<<<4096, 256, 0, stream>>>(x, Wq, Wk, Wv, Wo, xb, Wqb, Wkb, Wvb, Wob);

    gemm_qkv<<<dim3(16, 32), 384, 0, stream>>>(xb, Wqb, Wkb, Wvb, bq, bk, bv,
                                               tau, Qb, Kb, Vtb);

    attn_fwd<<<256, 512, 0, stream>>>(Qb, Kb, Vtb, tau, AOb);

    gemm_out<<<256, 256, 0, stream>>>(AOb, Wob, bo, (float*)d_out);
}

// Round 39
// 97.742 us; speedup vs baseline: 1.0388x; 1.0388x over previous
//
#include <hip/hip_runtime.h>
#include <hip/hip_bf16.h>
#include <cstdint>

#define BB 2
#define TT 2048
#define DMo 1024
#define NH 16
#define HD 64
#define NR (BB*TT)   // 4096 rows

typedef __attribute__((ext_vector_type(8))) short bf16x8;
typedef __attribute__((ext_vector_type(4))) float f32x4;
typedef __attribute__((ext_vector_type(16))) float f32x16;
typedef __attribute__((ext_vector_type(4))) unsigned short u16x4;

static __device__ __forceinline__ float bf2f(unsigned short u) {
    union { unsigned int u32; float f; } x; x.u32 = ((unsigned int)u) << 16; return x.f;
}
static __device__ __forceinline__ unsigned short f2bf(float f) {
    union { float f; unsigned int u; } x; x.f = f;
    unsigned int r = x.u + 0x7fffu + ((x.u >> 16) & 1u);
    return (unsigned short)(r >> 16);
}
// HW packed f32->bf16 (RNE), one VALU op for two values (T12 recipe)
static __device__ __forceinline__ unsigned int cvtpk(float lo, float hi) {
    unsigned int r;
    asm("v_cvt_pk_bf16_f32 %0, %1, %2" : "=v"(r) : "v"(lo), "v"(hi));
    return r;
}

static __device__ __forceinline__ void gload16(const unsigned short* g, unsigned short* l) {
    __builtin_amdgcn_global_load_lds((const __attribute__((address_space(1))) void*)g,
                                     (__attribute__((address_space(3))) void*)l, 16, 0, 0);
}

// ---------------- fused f32 -> bf16 convert for x + 4 weights ----------------
__global__ void cvt_all(const float* __restrict__ x, const float* __restrict__ wq,
                        const float* __restrict__ wk, const float* __restrict__ wv,
                        const float* __restrict__ wo,
                        unsigned short* __restrict__ xb, unsigned short* __restrict__ wqb,
                        unsigned short* __restrict__ wkb, unsigned short* __restrict__ wvb,
                        unsigned short* __restrict__ wob) {
    int bi = blockIdx.x;
    const float* src; unsigned short* dst; int base;
    if (bi < 2048)      { src = x;  dst = xb;  base = 0; }
    else if (bi < 2560) { src = wq; dst = wqb; base = 2048; }
    else if (bi < 3072) { src = wk; dst = wkb; base = 2560; }
    else if (bi < 3584) { src = wv; dst = wvb; base = 3072; }
    else                { src = wo; dst = wob; base = 3584; }
    size_t i = (size_t)(bi - base) * 256 + threadIdx.x;   // 8-elem groups
    const float4* p = reinterpret_cast<const float4*>(src) + 2 * i;
    float4 a = p[0], b = p[1];
    bf16x8 o;
    o[0] = (short)f2bf(a.x); o[1] = (short)f2bf(a.y); o[2] = (short)f2bf(a.z); o[3] = (short)f2bf(a.w);
    o[4] = (short)f2bf(b.x); o[5] = (short)f2bf(b.y); o[6] = (short)f2bf(b.z); o[7] = (short)f2bf(b.w);
    *(reinterpret_cast<bf16x8*>(dst) + i) = o;
}

// ---------------- fused QKV GEMM: BM=128 x BN=192, 384 thr (R32-proven) ------
__global__ __launch_bounds__(384, 3) void gemm_qkv(
    const unsigned short* __restrict__ A,
    const unsigned short* __restrict__ Wq,
    const unsigned short* __restrict__ Wk,
    const unsigned short* __restrict__ Wv,
    const float* __restrict__ bq, const float* __restrict__ bk, const float* __restrict__ bv,
    const float* __restrict__ tau,
    unsigned short* __restrict__ Qb, unsigned short* __restrict__ Kb,
    unsigned short* __restrict__ Vtb)
{
    __shared__ unsigned short lA[2][128 * 32];
    __shared__ unsigned short lB[2][192 * 32];
    const int K = DMo;
    int tid = threadIdx.x, lane = tid & 63, wid = tid >> 6;
    int l15 = lane & 15, l4 = lane >> 4;
    int wr = wid / 3, wc = wid % 3;           // 2 x 3 wave grid
    int pn = blockIdx.x, bm = blockIdx.y;     // pn 0..15 (192-col panels)
    f32x4 acc[4][4] = {};
    int sA0 = tid, sA1 = tid + 384;
    int rA0 = sA0 >> 2, cA0 = sA0 & 3;
    int rA1 = sA1 >> 2, cA1 = sA1 & 3;
    const unsigned short* pA0 = A + (size_t)(bm * 128 + rA0) * K + ((cA0 ^ (rA0 & 3)) * 8);
    const unsigned short* pA1 = A + (size_t)(bm * 128 + rA1) * K + ((cA1 ^ (rA1 & 3)) * 8);
    int sB0 = tid, sB1 = tid + 384;
    int rB0 = sB0 >> 2, cB0 = sB0 & 3;
    int rB1 = sB1 >> 2, cB1 = sB1 & 3;
    int gr0 = pn * 192 + rB0, gr1 = pn * 192 + rB1;
    int mm0 = gr0 >> 10, mm1 = gr1 >> 10;
    const unsigned short* W0 = (mm0 == 0) ? Wq : ((mm0 == 1) ? Wk : Wv);
    const unsigned short* W1 = (mm1 == 0) ? Wq : ((mm1 == 1) ? Wk : Wv);
    const unsigned short* pB0 = W0 + (size_t)(gr0 & 1023) * K + ((cB0 ^ (rB0 & 3)) * 8);
    const unsigned short* pB1 = W1 + (size_t)(gr1 & 1023) * K + ((cB1 ^ (rB1 & 3)) * 8);
    unsigned short* dA0h0 = lA[0] + sA0 * 8;
    unsigned short* dA1h0 = lA[0] + sA1 * 8;
    unsigned short* dA0h1 = lA[1] + sA0 * 8;
    unsigned short* dA1h1 = lA[1] + sA1 * 8;
    unsigned short* dB0h0 = lB[0] + sB0 * 8;
    unsigned short* dB1h0 = lB[0] + sB1 * 8;
    unsigned short* dB0h1 = lB[1] + sB0 * 8;
    unsigned short* dB1h1 = lB[1] + sB1 * 8;
    int cs = (l4 ^ (l15 & 3)) * 8;             // matching read-side XOR
    bool a2 = (tid < 128);                     // waves 0-1 (wave-uniform)
    for (int k0 = 0; k0 < K; k0 += 64) {
        gload16(pA0 + k0,      dA0h0);
        if (a2) gload16(pA1 + k0,      dA1h0);
        gload16(pA0 + k0 + 32, dA0h1);
        if (a2) gload16(pA1 + k0 + 32, dA1h1);
        gload16(pB0 + k0,      dB0h0);
        gload16(pB1 + k0,      dB1h0);
        gload16(pB0 + k0 + 32, dB0h1);
        gload16(pB1 + k0 + 32, dB1h1);
        __syncthreads();                 // drains vmcnt(0) + barrier (m97-proven)
#pragma unroll
        for (int kk = 0; kk < 2; ++kk) {
            bf16x8 af[4], bfr[4];
#pragma unroll
            for (int m = 0; m < 4; ++m) af[m]  = *(const bf16x8*)(lA[kk] + (wr * 64 + m * 16 + l15) * 32 + cs);
#pragma unroll
            for (int n = 0; n < 4; ++n) bfr[n] = *(const bf16x8*)(lB[kk] + (wc * 64 + n * 16 + l15) * 32 + cs);
#pragma unroll
            for (int m = 0; m < 4; ++m)
#pragma unroll
                for (int n = 0; n < 4; ++n)
                    acc[m][n] = __builtin_amdgcn_mfma_f32_16x16x32_bf16(af[m], bfr[n], acc[m][n], 0, 0, 0);
        }
        __syncthreads();
    }
    int gcolb = pn * 192 + wc * 64;
    int sel = gcolb >> 10;
    int cb = gcolb & 1023;                     // within-matrix col base
    const float* bias = (sel == 0) ? bq : ((sel == 1) ? bk : bv);
    float bz[4];
#pragma unroll
    for (int n = 0; n < 4; ++n) bz[n] = bias[cb + n * 16 + l15];
    if (sel < 2) {
        unsigned short* Ob = (sel == 0) ? Qb : Kb;
        float tscale = (sel == 0) ? tau[cb >> 6] : 1.0f;
#pragma unroll
        for (int m = 0; m < 4; ++m) {
            int row = bm * 128 + wr * 64 + m * 16 + l4 * 4;
#pragma unroll
            for (int i = 0; i < 4; ++i) {
                float v[4]; float ss = 0.f;
#pragma unroll
                for (int n = 0; n < 4; ++n) { v[n] = acc[m][n][i] + bz[n]; ss += v[n] * v[n]; }
#pragma unroll
                for (int off = 1; off < 16; off <<= 1) ss += __shfl_xor(ss, off);
                float sc = tscale / fmaxf(sqrtf(ss), 1e-12f);
#pragma unroll
                for (int n = 0; n < 4; ++n)
                    Ob[(size_t)(row + i) * DMo + cb + n * 16 + l15] = f2bf(v[n] * sc);
            }
        }
    } else {
#pragma unroll
        for (int m = 0; m < 4; ++m) {
            int row = bm * 128 + wr * 64 + m * 16 + l4 * 4;
#pragma unroll
            for (int n = 0; n < 4; ++n) {
                int col = cb + n * 16 + l15;
                u16x4 pk;
#pragma unroll
                for (int i = 0; i < 4; ++i) pk[i] = f2bf(acc[m][n][i] + bz[n]);
                int b = row >> 11, t = row & 2047;
                int bh = b * NH + (col >> 6), d = col & 63;
                *reinterpret_cast<u16x4*>(Vtb + ((size_t)bh * HD + d) * TT + t) = pk;
            }
        }
    }
}

// ---------------- final GEMM: BM=128 x BN=64, 512 blocks = 2/CU --------------
// R32 mechanism ported: grid 32x16 = 512 -> exactly 2 blocks/CU; the
// co-resident block's MFMA covers this block's staging drain (staging ~237cyc
// L2-bound > MFMA ~155cyc per iter at 1 block/CU -> pipe idles every barrier).
// Same K-order per output element as before -> bit-exact result.
__global__ __launch_bounds__(256) void gemm_out(
    const unsigned short* __restrict__ A,
    const unsigned short* __restrict__ Bm,
    const float* __restrict__ bias,
    float* __restrict__ Cout)
{
    __shared__ unsigned short lA[2][128 * 32];   // 16 KB
    __shared__ unsigned short lB[2][64 * 32];    //  8 KB
    const int K = DMo, N = DMo;
    int tid = threadIdx.x, lane = tid & 63, wid = tid >> 6;
    int l15 = lane & 15, l4 = lane >> 4;
    int wr = wid >> 1, wc = wid & 1;       // 2x2 waves: 64x32 out each
    int lid = blockIdx.x;
    int xcd = lid & 7, idx = lid >> 3;     // idx 0..63
    int bn = idx & 15;                     // 16 N-panels of 64
    int bm = (idx >> 4) * 8 + xcd;         // XCD-affine A-panel (0..31)
    f32x4 acc[4][2] = {};
    int sr = tid >> 2;
    int g8 = ((tid & 3) ^ (sr & 3)) * 8;
    const unsigned short* Ar0 = A + (size_t)(bm * 128 + sr) * K + g8;
    const unsigned short* Ar1 = Ar0 + (size_t)64 * K;
    const unsigned short* Br0 = Bm + (size_t)(bn * 64 + sr) * K + g8;
    unsigned short* lA0 = lA[0] + tid * 8;
    unsigned short* lA1 = lA[1] + tid * 8;
    unsigned short* lB0 = lB[0] + tid * 8;
    unsigned short* lB1 = lB[1] + tid * 8;
    int cs = (l4 ^ (l15 & 3)) * 8;
    for (int k0 = 0; k0 < K; k0 += 64) {
        gload16(Ar0 + k0,      lA0);
        gload16(Ar1 + k0,      lA0 + 2048);
        gload16(Ar0 + k0 + 32, lA1);
        gload16(Ar1 + k0 + 32, lA1 + 2048);
        gload16(Br0 + k0,      lB0);
        gload16(Br0 + k0 + 32, lB1);
        __syncthreads();
        __builtin_amdgcn_s_setprio(1);     // T5: 2-block role-split regime
#pragma unroll
        for (int kk = 0; kk < 2; ++kk) {
            bf16x8 af[4], bfr[2];
#pragma unroll
            for (int m = 0; m < 4; ++m) af[m]  = *(const bf16x8*)(lA[kk] + (wr * 64 + m * 16 + l15) * 32 + cs);
#pragma unroll
            for (int n = 0; n < 2; ++n) bfr[n] = *(const bf16x8*)(lB[kk] + (wc * 32 + n * 16 + l15) * 32 + cs);
#pragma unroll
            for (int m = 0; m < 4; ++m)
#pragma unroll
                for (int n = 0; n < 2; ++n)
                    acc[m][n] = __builtin_amdgcn_mfma_f32_16x16x32_bf16(af[m], bfr[n], acc[m][n], 0, 0, 0);
        }
        __builtin_amdgcn_s_setprio(0);
        __syncthreads();
    }
#pragma unroll
    for (int m = 0; m < 4; ++m) {
        int row = bm * 128 + wr * 64 + m * 16 + l4 * 4;
#pragma unroll
        for (int n = 0; n < 2; ++n) {
            int col = bn * 64 + wc * 32 + n * 16 + l15;
            float bz = bias[col];
#pragma unroll
            for (int i = 0; i < 4; ++i)
                Cout[(size_t)(row + i) * N + col] = acc[m][n][i] + bz;
        }
    }
}

// ---------------- flash attention: 8 waves, kv split across wave-groups ------
// (R30-proven; 256 blocks, two sequential qb phases per block)
__global__ __launch_bounds__(512, 1) void attn_fwd(
    const unsigned short* __restrict__ Qn,
    const unsigned short* __restrict__ Kn,
    const unsigned short* __restrict__ Vt,
    const float* __restrict__ tau,
    unsigned short* __restrict__ Out)
{
    __shared__ unsigned short lK[2][2][64][68];   // [ring][parity][row][col]
    __shared__ unsigned short lVt[2][2][64][68];
    __shared__ float lX[4][64][34];               // cross-group exchange
    __shared__ float lInv[4][32];
    int bid = blockIdx.x;
    int xcd = bid & 7, r = bid >> 3;     // r 0..31
    int bh = ((r & 3) << 3) + xcd;
    int jid = r >> 2;                    // 0..7
    int b = bh >> 4, h = bh & 15;
    int tid = threadIdx.x, lane = tid & 63, wid = tid >> 6;
    int grp = wid >> 2, w4 = wid & 3;    // kv-group, q-tile within group
    int l31 = lane & 31, half = lane >> 5;
    float M = fabsf(tau[h]);             // fixed softmax shift

    const unsigned short* Kg = Kn + (size_t)b * TT * DMo + h * HD;
    const unsigned short* Vg = Vt + (size_t)bh * HD * TT;

    int rA = tid >> 3, gA = (tid & 7) * 8;   // 512 thr: 64 rows x 8 chunks

    for (int ph = 0; ph < 2; ++ph) {
        int qb = ph ? jid : (15 - jid);
        int q0 = qb * 128;
        int nt = 2 * qb + 2;
        int nh2 = nt >> 1;               // tiles per group (nt always even)

        size_t qoff = ((size_t)b * TT + q0 + w4 * 32 + l31) * DMo + h * HD;
        bf16x8 qf[4];
#pragma unroll
        for (int ks = 0; ks < 4; ++ks)
            qf[ks] = *(const bf16x8*)(Qn + qoff + ks * 16 + half * 8);

        f32x16 accO[2] = {};
        float l_run = 0.f;

        bf16x8 rk0, rk1, rv0, rv1;       // staging regs for a tile PAIR
        auto ldpair = [&](int jp) {      // tiles 2jp, 2jp+1
            rk0 = *(const bf16x8*)(Kg + (size_t)(2 * jp * 64 + rA) * DMo + gA);
            rk1 = *(const bf16x8*)(Kg + (size_t)((2 * jp + 1) * 64 + rA) * DMo + gA);
            rv0 = *(const bf16x8*)(Vg + (size_t)rA * TT + 2 * jp * 64 + gA);
            rv1 = *(const bf16x8*)(Vg + (size_t)rA * TT + (2 * jp + 1) * 64 + gA);
        };
        auto stpair = [&](int pb) {
            *reinterpret_cast<bf16x8*>(&lK[pb][0][rA][gA])  = rk0;
            *reinterpret_cast<bf16x8*>(&lK[pb][1][rA][gA])  = rk1;
            *reinterpret_cast<bf16x8*>(&lVt[pb][0][rA][gA]) = rv0;
            *reinterpret_cast<bf16x8*>(&lVt[pb][1][rA][gA]) = rv1;
        };
        ldpair(0);
        if (ph == 1) __syncthreads();    // prior phase fully done before ring reuse
        stpair(0);
        if (nh2 > 1) ldpair(1);

        for (int t2 = 0; t2 < nh2; ++t2) {
            int cur = t2 & 1;
            __syncthreads();             // ring[cur] visible; prior reads done
            if (t2 + 1 < nh2) {
                stpair(cur ^ 1);
                if (t2 + 2 < nh2) ldpair(t2 + 2);
            }
            int j = 2 * t2 + grp;        // this group's kv tile
            // S^T = K . Q
            f32x16 s[2] = {};
            __builtin_amdgcn_s_setprio(1);
#pragma unroll
            for (int kvb = 0; kvb < 2; ++kvb)
#pragma unroll
                for (int ks = 0; ks < 4; ++ks) {
                    bf16x8 a = *(const bf16x8*)(&lK[cur][grp][kvb * 32 + l31][ks * 16 + half * 8]);
                    s[kvb] = __builtin_amdgcn_mfma_f32_32x32x16_bf16(a, qf[ks], s[kvb], 0, 0, 0);
                }
            __builtin_amdgcn_s_setprio(0);
            // causal mask only on the diagonal pair (last step; both groups)
            if (t2 == nh2 - 1) {
                int qg = q0 + w4 * 32 + l31;
#pragma unroll
                for (int kvb = 0; kvb < 2; ++kvb)
#pragma unroll
                    for (int rr = 0; rr < 16; ++rr) {
                        int kvg = j * 64 + kvb * 32 + (rr & 3) + 8 * (rr >> 2) + 4 * half;
                        if (kvg > qg) s[kvb][rr] = -1e30f;
                    }
            }
            // fixed-shift softmax; lane-local denominator
            float rs = 0.f;
#pragma unroll
            for (int kvb = 0; kvb < 2; ++kvb)
#pragma unroll
                for (int rr = 0; rr < 16; ++rr) {
                    float p = __expf(s[kvb][rr] - M); s[kvb][rr] = p; rs += p;
                }
            l_run += rs;
            // pack P via v_cvt_pk_bf16_f32
            unsigned int Wp[2][4][2];
#pragma unroll
            for (int kvb = 0; kvb < 2; ++kvb)
#pragma unroll
                for (int jj = 0; jj < 4; ++jj)
#pragma unroll
                    for (int t = 0; t < 2; ++t)
                        Wp[kvb][jj][t] = cvtpk(s[kvb][4 * jj + 2 * t], s[kvb][4 * jj + 2 * t + 1]);
            // build PV A-fragments (permlane32_swap exchanges lane halves)
            bf16x8 pa[4];
#pragma unroll
            for (int kvs = 0; kvs < 4; ++kvs) {
                int c = kvs >> 1, d0 = 2 * (kvs & 1), d1 = d0 + 1;
                unsigned int A0 = half ? Wp[c][d1][0] : Wp[c][d0][0];
                unsigned int A1 = half ? Wp[c][d1][1] : Wp[c][d0][1];
                unsigned int B0 = half ? Wp[c][d0][0] : Wp[c][d1][0];
                unsigned int B1 = half ? Wp[c][d0][1] : Wp[c][d1][1];
                unsigned int x0 = B0, y0 = B0, x1 = B1, y1 = B1;
                asm volatile("v_permlane32_swap_b32 %0, %1" : "+v"(x0), "+v"(y0));
                asm volatile("v_permlane32_swap_b32 %0, %1" : "+v"(x1), "+v"(y1));
                unsigned int P0 = half ? x0 : y0;
                unsigned int P1 = half ? x1 : y1;
                unsigned int paw[4];
                paw[0] = half ? P0 : A0;
                paw[1] = half ? P1 : A1;
                paw[2] = half ? A0 : P0;
                paw[3] = half ? A1 : P1;
                pa[kvs] = *reinterpret_cast<bf16x8*>(paw);
            }
            // O += P . V
            __builtin_amdgcn_s_setprio(1);
#pragma unroll
            for (int dblk = 0; dblk < 2; ++dblk)
#pragma unroll
                for (int kvs = 0; kvs < 4; ++kvs) {
                    bf16x8 bv = *(const bf16x8*)(&lVt[cur][grp][dblk * 32 + l31][kvs * 16 + half * 8]);
                    accO[dblk] = __builtin_amdgcn_mfma_f32_32x32x16_bf16(pa[kvs], bv, accO[dblk], 0, 0, 0);
                }
            __builtin_amdgcn_s_setprio(0);
        }
        // within-wave kv-half combine
        l_run += __shfl_xor(l_run, 32);
        // cross-group combine via LDS: group 1 -> group 0
        if (grp == 1) {
#pragma unroll
            for (int dblk = 0; dblk < 2; ++dblk)
#pragma unroll
                for (int rr = 0; rr < 16; ++rr)
                    lX[w4][lane][dblk * 16 + rr] = accO[dblk][rr];
            if (lane < 32) lX[w4][lane][32] = l_run;
        }
        __syncthreads();
        if (grp == 0) {
#pragma unroll
            for (int dblk = 0; dblk < 2; ++dblk)
#pragma unroll
                for (int rr = 0; rr < 16; ++rr)
                    accO[dblk][rr] += lX[w4][lane][dblk * 16 + rr];
            l_run += lX[w4][l31][32];
            float inv = 1.0f / l_run;
            if (lane < 32) lInv[w4][l31] = inv;   // wave-private slice
            asm volatile("s_waitcnt lgkmcnt(0)" ::: "memory");
            __builtin_amdgcn_sched_barrier(0);
#pragma unroll
            for (int rr = 0; rr < 16; ++rr) {
                int qrow = (rr & 3) + 8 * (rr >> 2) + 4 * half;
                float iv = lInv[w4][qrow];
                size_t rowoff = (size_t)(b * TT + q0 + w4 * 32 + qrow) * DMo + h * HD + l31;
#pragma unroll
                for (int dblk = 0; dblk < 2; ++dblk)
                    Out[rowoff + dblk * 32] = f2bf(accO[dblk][rr] * iv);
            }
        }
    }
}

extern "C" void kernel_launch(void* const* d_in, const int* in_sizes, int n_in,
                              void* d_out, int out_size, void* d_ws, size_t ws_size,
                              hipStream_t stream) {
    const float* x   = (const float*)d_in[0];
    // d_in[1] = mask: pure causal -1e9, handled analytically in attn_fwd
    const float* Wq  = (const float*)d_in[2];
    const float* bq  = (const float*)d_in[3];
    const float* Wk  = (const float*)d_in[4];
    const float* bk  = (const float*)d_in[5];
    const float* Wv  = (const float*)d_in[6];
    const float* bv  = (const float*)d_in[7];
    const float* Wo  = (const float*)d_in[8];
    const float* bo  = (const float*)d_in[9];
    const float* tau = (const float*)d_in[10];

    char* ws = (char*)d_ws;
    unsigned short* xb  = (unsigned short*)(ws);
    unsigned short* Wqb = (unsigned short*)(ws + ((size_t)8  << 20));
    unsigned short* Wkb = (unsigned short*)(ws + ((size_t)10 << 20));
    unsigned short* Wvb = (unsigned short*)(ws + ((size_t)12 << 20));
    unsigned short* Wob = (unsigned short*)(ws + ((size_t)14 << 20));
    unsigned short* Qb  = (unsigned short*)(ws + ((size_t)16 << 20));
    unsigned short* Kb  = (unsigned short*)(ws + ((size_t)24 << 20));
    unsigned short* Vtb = (unsigned short*)(ws + ((size_t)32 << 20));
    unsigned short* AOb = (unsigned short*)(ws + ((size_t)40 << 20));

    cvt_all<<<4096, 256, 0, stream>>>(x, Wq, Wk, Wv, Wo, xb, Wqb, Wkb, Wvb, Wob);

    gemm_qkv<<<dim3(16, 32), 384, 0, stream>>>(xb, Wqb, Wkb, Wvb, bq, bk, bv,
                                               tau, Qb, Kb, Vtb);

    attn_fwd<<<256, 512, 0, stream>>>(Qb, Kb, Vtb, tau, AOb);

    gemm_out<<<512, 256, 0, stream>>>(AOb, Wob, bo, (float*)d_out);
}